// Round 1
// baseline (723.102 us; speedup 1.0000x reference)
//
#include <hip/hip_runtime.h>
#include <math.h>

#define HDIM 128
#define TM 64   // edges per block in the fused MLP kernel

__device__ __forceinline__ float gelu_exact(float x) {
    return 0.5f * x * (1.0f + erff(x * 0.70710678118654752440f));
}

// ---------------- stable counting-sort kernels ----------------

// per-chunk (1024 edges) group histogram
__global__ void k_hist(const int* __restrict__ groups, int E, int* __restrict__ counts) {
    __shared__ int c[3];
    int t = threadIdx.x;
    if (t < 3) c[t] = 0;
    __syncthreads();
    int base = blockIdx.x * 1024;
    for (int i = t; i < 1024; i += 256) {
        int e = base + i;
        if (e < E) atomicAdd(&c[groups[e]], 1);
    }
    __syncthreads();
    if (t < 3) counts[blockIdx.x * 3 + t] = c[t];
}

// exclusive scan of per-chunk counts: one wave per group (3 waves)
__global__ void k_scan(const int* __restrict__ counts, int nChunks,
                       int* __restrict__ bbase, int* __restrict__ gstart, int E) {
    __shared__ int tot[3];
    int t = threadIdx.x;         // block = 192
    int lane = t & 63;
    int g = t >> 6;              // 0..2
    int carry = 0;
    for (int base = 0; base < nChunks; base += 64) {
        int b = base + lane;
        int v = (b < nChunks) ? counts[b * 3 + g] : 0;
        int sc = v;
        #pragma unroll
        for (int off = 1; off < 64; off <<= 1) {
            int u = __shfl_up(sc, off);
            if (lane >= off) sc += u;
        }
        if (b < nChunks) bbase[b * 3 + g] = carry + sc - v;
        carry += __shfl(sc, 63);
    }
    if (lane == 0) tot[g] = carry;
    __syncthreads();
    if (t == 0) {
        gstart[0] = 0;
        gstart[1] = tot[0];
        gstart[2] = tot[0] + tot[1];
        gstart[3] = E;
    }
}

// stable rank within chunk via ballot; scatter edge ids to sorted positions
__global__ void k_scatter(const int* __restrict__ groups, int E,
                          const int* __restrict__ bbase, const int* __restrict__ gstart,
                          int* __restrict__ sorted) {
    int b = blockIdx.x;
    int lane = threadIdx.x;  // block = 64 (one wave)
    int run0 = gstart[0] + bbase[b * 3 + 0];
    int run1 = gstart[1] + bbase[b * 3 + 1];
    int run2 = gstart[2] + bbase[b * 3 + 2];
    unsigned long long lt = (1ull << lane) - 1ull;
    for (int p = 0; p < 16; ++p) {
        int e = b * 1024 + p * 64 + lane;
        int g = (e < E) ? groups[e] : 3;
        unsigned long long m0 = __ballot(g == 0);
        unsigned long long m1 = __ballot(g == 1);
        unsigned long long m2 = __ballot(g == 2);
        int pos = 0;
        if (g == 0) pos = run0 + __popcll(m0 & lt);
        else if (g == 1) pos = run1 + __popcll(m1 & lt);
        else if (g == 2) pos = run2 + __popcll(m2 & lt);
        if (e < E) sorted[pos] = e;
        run0 += __popcll(m0);
        run1 += __popcll(m1);
        run2 += __popcll(m2);
    }
}

// ---------------- fused per-edge MLP ----------------
// block: 256 threads, TM=64 edges (contiguous sorted positions -> ~uniform group)
// GEMM1: [64 x 256] x [256 x 128], BK=32, per-thread 4x8 acc
// then bias+LN+GELU in regs (shfl over 16 lanes/row), h^T -> LDS,
// GEMM2: [64 x 128] x [128 x 64], BK=64, per-thread 4x4 acc,
// then GELU + dot(W3) + shfl reduce + write to sorted position.
__global__ __launch_bounds__(256, 3)
void k_mlp(const float* __restrict__ emb,
           const int* __restrict__ edges,
           const int* __restrict__ sorted,
           const int* __restrict__ gstart,
           const float* __restrict__ W1, const float* __restrict__ b1,
           const float* __restrict__ lng, const float* __restrict__ lnb,
           const float* __restrict__ W2, const float* __restrict__ b2,
           const float* __restrict__ W3, const float* __restrict__ b3,
           float* __restrict__ out, int E)
{
    // phase1: sA [32][68] @0 (2176 f), sB [32][132] @2176 (4224 f)
    // phase2: sHT [128][68] @0 (8704 f), sW2 [64][68] @8704 (4352 f)
    __shared__ float smem[13056];          // 52224 B -> 3 blocks/CU
    __shared__ int s_u[TM], s_v[TM], s_gs[4];

    float* sA  = smem;
    float* sB  = smem + 2176;
    float* sHT = smem;
    float* sW2 = smem + 8704;

    const int t = threadIdx.x;
    const int pos0 = blockIdx.x * TM;

    if (t < 4) s_gs[t] = gstart[t];
    if (t < TM) {
        int p = pos0 + t;
        int e = sorted[p < E ? p : 0];
        s_u[t] = edges[2 * e];
        s_v[t] = edges[2 * e + 1];
    }
    __syncthreads();

    int plast = pos0 + TM - 1; if (plast >= E) plast = E - 1;
    int g0 = (pos0  >= s_gs[2]) ? 2 : (pos0  >= s_gs[1]) ? 1 : 0;
    int g1 = (plast >= s_gs[2]) ? 2 : (plast >= s_gs[1]) ? 1 : 0;

    const int ty = t >> 4;   // 0..15: rows ty*4..+3
    const int tx = t & 15;   // cols: GEMM1 tx*8..+7, GEMM2 tx*4..+3

    const int lm  = t >> 2;  // A-gather: row 0..63
    const int lkq = t & 3;   // A-gather: 8-float segment
    const int bk  = t >> 3;  // B-stage: k row 0..31
    const int bnq = t & 7;   // B-stage: 16-float segment

    for (int g = g0; g <= g1; ++g) {
        float acc[4][8];
        #pragma unroll
        for (int i = 0; i < 4; ++i)
            #pragma unroll
            for (int j = 0; j < 8; ++j) acc[i][j] = 0.0f;

        const float* W1g = W1 + (size_t)g * 256 * HDIM;

        for (int kt = 0; kt < 8; ++kt) {
            // stage A: gather ee[m][kt*32 .. +31] (k<128 from emb[u], else emb[v])
            {
                int gk = kt * 32 + lkq * 8;
                int node = (gk < HDIM) ? s_u[lm] : s_v[lm];
                const float* rp = emb + (size_t)node * HDIM + (gk & (HDIM - 1));
                float4 v0 = *(const float4*)(rp);
                float4 v1 = *(const float4*)(rp + 4);
                int kk0 = lkq * 8;
                sA[(kk0 + 0) * 68 + lm] = v0.x;
                sA[(kk0 + 1) * 68 + lm] = v0.y;
                sA[(kk0 + 2) * 68 + lm] = v0.z;
                sA[(kk0 + 3) * 68 + lm] = v0.w;
                sA[(kk0 + 4) * 68 + lm] = v1.x;
                sA[(kk0 + 5) * 68 + lm] = v1.y;
                sA[(kk0 + 6) * 68 + lm] = v1.z;
                sA[(kk0 + 7) * 68 + lm] = v1.w;
            }
            // stage B: W1[g][kt*32+bk][:]
            {
                const float* wp = W1g + (size_t)(kt * 32 + bk) * HDIM + bnq * 16;
                float* dp = sB + bk * 132 + bnq * 16;
                #pragma unroll
                for (int i = 0; i < 4; ++i)
                    *(float4*)(dp + 4 * i) = *(const float4*)(wp + 4 * i);
            }
            __syncthreads();
            #pragma unroll 8
            for (int kk = 0; kk < 32; ++kk) {
                float a[4], b[8];
                *(float4*)&a[0] = *(const float4*)&sA[kk * 68 + ty * 4];
                *(float4*)&b[0] = *(const float4*)&sB[kk * 132 + tx * 8];
                *(float4*)&b[4] = *(const float4*)&sB[kk * 132 + tx * 8 + 4];
                #pragma unroll
                for (int i = 0; i < 4; ++i)
                    #pragma unroll
                    for (int j = 0; j < 8; ++j)
                        acc[i][j] = fmaf(a[i], b[j], acc[i][j]);
            }
            __syncthreads();
        }

        // bias + LayerNorm + GELU, all in registers (row = 16 lanes: tx group)
        {
            float b1v[8], lgv[8], lbv[8];
            #pragma unroll
            for (int j = 0; j < 8; ++j) {
                int c = tx * 8 + j;
                b1v[j] = b1[g * HDIM + c];
                lgv[j] = lng[g * HDIM + c];
                lbv[j] = lnb[g * HDIM + c];
            }
            #pragma unroll
            for (int i = 0; i < 4; ++i) {
                float s = 0.f, s2 = 0.f;
                #pragma unroll
                for (int j = 0; j < 8; ++j) {
                    float x = acc[i][j] + b1v[j];
                    acc[i][j] = x;
                    s += x; s2 += x * x;
                }
                #pragma unroll
                for (int off = 1; off < 16; off <<= 1) {
                    s  += __shfl_xor(s,  off);
                    s2 += __shfl_xor(s2, off);
                }
                float mu  = s  * (1.0f / HDIM);
                float var = s2 * (1.0f / HDIM) - mu * mu;
                float rs  = rsqrtf(var + 1e-5f);
                #pragma unroll
                for (int j = 0; j < 8; ++j) {
                    float x = (acc[i][j] - mu) * rs * lgv[j] + lbv[j];
                    acc[i][j] = gelu_exact(x);
                }
            }
        }

        // write h transposed: sHT[c][m]
        #pragma unroll
        for (int j = 0; j < 8; ++j) {
            int c = tx * 8 + j;
            #pragma unroll
            for (int i = 0; i < 4; ++i)
                sHT[c * 68 + ty * 4 + i] = acc[i][j];
        }
        __syncthreads();

        // GEMM2: 64x64, K=128, two K-tiles of 64
        float acc2[4][4];
        #pragma unroll
        for (int i = 0; i < 4; ++i)
            #pragma unroll
            for (int j = 0; j < 4; ++j) acc2[i][j] = 0.0f;

        for (int kt2 = 0; kt2 < 2; ++kt2) {
            {
                int kk2 = t >> 2;          // 0..63
                int nq  = t & 3;           // x16
                const float* wp = W2 + ((size_t)g * HDIM + kt2 * 64 + kk2) * 64 + nq * 16;
                float* dp = sW2 + kk2 * 68 + nq * 16;
                #pragma unroll
                for (int i = 0; i < 4; ++i)
                    *(float4*)(dp + 4 * i) = *(const float4*)(wp + 4 * i);
            }
            __syncthreads();
            #pragma unroll 8
            for (int kk = 0; kk < 64; ++kk) {
                float a2[4], bb[4];
                *(float4*)&a2[0] = *(const float4*)&sHT[(kt2 * 64 + kk) * 68 + ty * 4];
                *(float4*)&bb[0] = *(const float4*)&sW2[kk * 68 + tx * 4];
                #pragma unroll
                for (int i = 0; i < 4; ++i)
                    #pragma unroll
                    for (int j = 0; j < 4; ++j)
                        acc2[i][j] = fmaf(a2[i], bb[j], acc2[i][j]);
            }
            __syncthreads();
        }

        // epilogue: GELU + dot W3 + reduce over 16 lanes + write
        {
            float b2v[4], w3v[4];
            #pragma unroll
            for (int j = 0; j < 4; ++j) {
                b2v[j] = b2[g * 64 + tx * 4 + j];
                w3v[j] = W3[g * 64 + tx * 4 + j];
            }
            float bias3 = b3[g];
            #pragma unroll
            for (int i = 0; i < 4; ++i) {
                float sacc = 0.f;
                #pragma unroll
                for (int j = 0; j < 4; ++j)
                    sacc += gelu_exact(acc2[i][j] + b2v[j]) * w3v[j];
                #pragma unroll
                for (int off = 1; off < 16; off <<= 1)
                    sacc += __shfl_xor(sacc, off);
                if (tx == 0) {
                    int p = pos0 + ty * 4 + i;
                    if (p >= s_gs[g] && p < s_gs[g + 1])
                        out[p] = sacc + bias3;
                }
            }
        }
        __syncthreads();   // protect LDS before next group iteration
    }
}

extern "C" void kernel_launch(void* const* d_in, const int* in_sizes, int n_in,
                              void* d_out, int out_size, void* d_ws, size_t ws_size,
                              hipStream_t stream) {
    const float* emb    = (const float*)d_in[0];
    const int*   edges  = (const int*)  d_in[1];
    const int*   groups = (const int*)  d_in[2];
    const float* W1     = (const float*)d_in[3];
    const float* b1     = (const float*)d_in[4];
    const float* lng    = (const float*)d_in[5];
    const float* lnb    = (const float*)d_in[6];
    const float* W2     = (const float*)d_in[7];
    const float* b2     = (const float*)d_in[8];
    const float* W3     = (const float*)d_in[9];
    const float* b3     = (const float*)d_in[10];
    float* out = (float*)d_out;
    int E = in_sizes[2];

    int nChunks = (E + 1023) / 1024;
    int* counts = (int*)d_ws;
    int* bbase  = counts + (size_t)nChunks * 3;
    int* gstart = bbase  + (size_t)nChunks * 3;
    int* sorted = gstart + 4;

    k_hist   <<<dim3(nChunks), dim3(256), 0, stream>>>(groups, E, counts);
    k_scan   <<<dim3(1),       dim3(192), 0, stream>>>(counts, nChunks, bbase, gstart, E);
    k_scatter<<<dim3(nChunks), dim3(64),  0, stream>>>(groups, E, bbase, gstart, sorted);

    int nTiles = (E + TM - 1) / TM;
    k_mlp<<<dim3(nTiles), dim3(256), 0, stream>>>(
        emb, edges, sorted, gstart, W1, b1, lng, lnb, W2, b2, W3, b3, out, E);
}

// Round 2
// 473.300 us; speedup vs baseline: 1.5278x; 1.5278x over previous
//
#include <hip/hip_runtime.h>
#include <math.h>
#include <stdint.h>

#define HDIM 128
#define TM 64   // edges per block in the fused MLP kernel

typedef short s16x8 __attribute__((ext_vector_type(8)));      // 8 bf16 (4 VGPRs) MFMA A/B frag
typedef float f32x4 __attribute__((ext_vector_type(4)));      // MFMA C/D frag
typedef unsigned short ushort8 __attribute__((ext_vector_type(8)));

__device__ __forceinline__ float gelu_exact(float x) {
    return 0.5f * x * (1.0f + erff(x * 0.70710678118654752440f));
}

// fp32 -> bf16 round-to-nearest-even (manual, no API-version risk)
__device__ __forceinline__ unsigned short f2bf(float x) {
    unsigned u = __float_as_uint(x);
    u += 0x7FFFu + ((u >> 16) & 1u);
    return (unsigned short)(u >> 16);
}

// ---------------- stable counting-sort kernels ----------------

__global__ void k_hist(const int* __restrict__ groups, int E, int* __restrict__ counts) {
    __shared__ int c[3];
    int t = threadIdx.x;
    if (t < 3) c[t] = 0;
    __syncthreads();
    int base = blockIdx.x * 1024;
    for (int i = t; i < 1024; i += 256) {
        int e = base + i;
        if (e < E) atomicAdd(&c[groups[e]], 1);
    }
    __syncthreads();
    if (t < 3) counts[blockIdx.x * 3 + t] = c[t];
}

__global__ void k_scan(const int* __restrict__ counts, int nChunks,
                       int* __restrict__ bbase, int* __restrict__ gstart, int E) {
    __shared__ int tot[3];
    int t = threadIdx.x;         // block = 192
    int lane = t & 63;
    int g = t >> 6;              // 0..2
    int carry = 0;
    for (int base = 0; base < nChunks; base += 64) {
        int b = base + lane;
        int v = (b < nChunks) ? counts[b * 3 + g] : 0;
        int sc = v;
        #pragma unroll
        for (int off = 1; off < 64; off <<= 1) {
            int u = __shfl_up(sc, off);
            if (lane >= off) sc += u;
        }
        if (b < nChunks) bbase[b * 3 + g] = carry + sc - v;
        carry += __shfl(sc, 63);
    }
    if (lane == 0) tot[g] = carry;
    __syncthreads();
    if (t == 0) {
        gstart[0] = 0;
        gstart[1] = tot[0];
        gstart[2] = tot[0] + tot[1];
        gstart[3] = E;
    }
}

__global__ void k_scatter(const int* __restrict__ groups, int E,
                          const int* __restrict__ bbase, const int* __restrict__ gstart,
                          int* __restrict__ sorted) {
    int b = blockIdx.x;
    int lane = threadIdx.x;  // block = 64 (one wave)
    int run0 = gstart[0] + bbase[b * 3 + 0];
    int run1 = gstart[1] + bbase[b * 3 + 1];
    int run2 = gstart[2] + bbase[b * 3 + 2];
    unsigned long long lt = (1ull << lane) - 1ull;
    for (int p = 0; p < 16; ++p) {
        int e = b * 1024 + p * 64 + lane;
        int g = (e < E) ? groups[e] : 3;
        unsigned long long m0 = __ballot(g == 0);
        unsigned long long m1 = __ballot(g == 1);
        unsigned long long m2 = __ballot(g == 2);
        int pos = 0;
        if (g == 0) pos = run0 + __popcll(m0 & lt);
        else if (g == 1) pos = run1 + __popcll(m1 & lt);
        else if (g == 2) pos = run2 + __popcll(m2 & lt);
        if (e < E) sorted[pos] = e;
        run0 += __popcll(m0);
        run1 += __popcll(m1);
        run2 += __popcll(m2);
    }
}

// ---------------- prep: transpose + convert W1, W2 to bf16 [g][n][k] ----------------
// W1T[g][n=128][k=256] from W1[g][k=256][n=128]; W2T[g][n=64][k=128] from W2[g][k][n].
__global__ void k_prep(const float* __restrict__ W1, const float* __restrict__ W2,
                       unsigned short* __restrict__ W1T, unsigned short* __restrict__ W2T) {
    int idx = blockIdx.x * 256 + threadIdx.x;
    if (idx < 3 * 32 * 128) {                    // W1T: task = (g, kc, n), n fastest (coalesced reads)
        int g  = idx >> 12;                      // /4096
        int r  = idx & 4095;
        int kc = r >> 7;                         // 0..31  (k0 = kc*8)
        int n  = r & 127;
        const float* src = W1 + (size_t)g * 256 * 128 + (size_t)(kc * 8) * 128 + n;
        ushort8 o;
        #pragma unroll
        for (int j = 0; j < 8; ++j) o[j] = f2bf(src[j * 128]);
        *(ushort8*)(W1T + ((size_t)(g * 128 + n)) * 256 + kc * 8) = o;
    } else if (idx < 3 * 32 * 128 + 3 * 16 * 64) {
        int r2 = idx - 3 * 32 * 128;             // W2T: task = (g, kc, n)
        int g  = r2 >> 10;                       // /1024
        int r  = r2 & 1023;
        int kc = r >> 6;                         // 0..15
        int n  = r & 63;
        const float* src = W2 + (size_t)g * 128 * 64 + (size_t)(kc * 8) * 64 + n;
        ushort8 o;
        #pragma unroll
        for (int j = 0; j < 8; ++j) o[j] = f2bf(src[j * 64]);
        *(ushort8*)(W2T + ((size_t)(g * 64 + n)) * 128 + kc * 8) = o;
    }
}

// ---------------- fused per-edge MLP (MFMA bf16) ----------------
// Block: 256 thr = 4 waves; TM=64 edges. Wave w owns edge rows 16w..16w+15.
// GEMM1: [64x256]x[256x128] via 16x16x32 bf16 MFMA, A from emb gather (fp32->bf16
// on the fly), B from bf16 W1T[g][n][k] direct-global. No LDS.
// Epilogue: bias+LN+GELU in regs (quad shfl), h -> LDS bf16 [m][136] (A-layout xform).
// GEMM2: [64x128]x[128x64], A from LDS, B from W2T direct-global.
// Epilogue: GELU + dot W3 + quad shfl reduce -> out[pos].
__global__ __launch_bounds__(256)
void k_mlp(const float* __restrict__ emb,
           const int* __restrict__ edges,
           const int* __restrict__ sorted,
           const int* __restrict__ gstart,
           const unsigned short* __restrict__ W1T,
           const float* __restrict__ b1,
           const float* __restrict__ lng, const float* __restrict__ lnb,
           const unsigned short* __restrict__ W2T,
           const float* __restrict__ b2,
           const float* __restrict__ W3, const float* __restrict__ b3,
           float* __restrict__ out, int E)
{
    __shared__ unsigned short sH[64 * 136];   // 17408 B; stride 136 -> A2-frag reads conflict-free

    const int t    = threadIdx.x;
    const int w    = t >> 6;        // wave 0..3
    const int lane = t & 63;
    const int n0   = lane & 15;     // MFMA "16" index (A row / B col / D col)
    const int quad = lane >> 4;     // MFMA k-quad (A/B) and D row-group

    const int pos0 = blockIdx.x * TM;

    // this lane's edge (A-frag row m = lane&15 is fixed per lane)
    int p_lane = pos0 + w * 16 + n0;
    int pc = p_lane < E ? p_lane : E - 1;
    int e  = sorted[pc];
    int u  = edges[2 * e];
    int v  = edges[2 * e + 1];
    const float* urow = emb + (size_t)u * HDIM;
    const float* vrow = emb + (size_t)v * HDIM;

    int gs1 = gstart[1], gs2 = gstart[2];
    int plast = (pos0 + TM - 1 < E) ? pos0 + TM - 1 : E - 1;
    int g0 = (pos0  >= gs2) ? 2 : (pos0  >= gs1) ? 1 : 0;
    int g1 = (plast >= gs2) ? 2 : (plast >= gs1) ? 1 : 0;

    for (int g = g0; g <= g1; ++g) {
        const unsigned short* W1Tg = W1T + (size_t)g * 128 * 256;

        f32x4 acc[8];
        #pragma unroll
        for (int nt = 0; nt < 8; ++nt) acc[nt] = (f32x4){0.f, 0.f, 0.f, 0.f};

        #pragma unroll
        for (int ks = 0; ks < 8; ++ks) {
            // A-frag: ee[m][ks*32 + quad*8 .. +7]; cols <128 from u-row, else v-row
            const float* ap = (ks < 4 ? urow : vrow) + ((ks * 32) & (HDIM - 1)) + quad * 8;
            float4 a0 = *(const float4*)ap;
            float4 a1 = *(const float4*)(ap + 4);
            union { ushort8 us; s16x8 fr; } A;
            A.us[0] = f2bf(a0.x); A.us[1] = f2bf(a0.y);
            A.us[2] = f2bf(a0.z); A.us[3] = f2bf(a0.w);
            A.us[4] = f2bf(a1.x); A.us[5] = f2bf(a1.y);
            A.us[6] = f2bf(a1.z); A.us[7] = f2bf(a1.w);
            s16x8 afrag = A.fr;
            #pragma unroll
            for (int nt = 0; nt < 8; ++nt) {
                s16x8 bfrag = *(const s16x8*)(W1Tg + (size_t)(nt * 16 + n0) * 256 + ks * 32 + quad * 8);
                acc[nt] = __builtin_amdgcn_mfma_f32_16x16x32_bf16(afrag, bfrag, acc[nt], 0, 0, 0);
            }
        }

        // bias + LayerNorm + GELU; D layout: row = quad*4+reg (in-wave), col = nt*16+n0
        {
            float b1v[8], lgv[8], lbv[8];
            #pragma unroll
            for (int nt = 0; nt < 8; ++nt) {
                int c = nt * 16 + n0;
                b1v[nt] = b1[g * HDIM + c];
                lgv[nt] = lng[g * HDIM + c];
                lbv[nt] = lnb[g * HDIM + c];
            }
            #pragma unroll
            for (int reg = 0; reg < 4; ++reg) {
                float s = 0.f, s2 = 0.f;
                float xv[8];
                #pragma unroll
                for (int nt = 0; nt < 8; ++nt) {
                    float x = acc[nt][reg] + b1v[nt];
                    xv[nt] = x; s += x; s2 += x * x;
                }
                #pragma unroll
                for (int off = 1; off < 16; off <<= 1) {
                    s  += __shfl_xor(s,  off);
                    s2 += __shfl_xor(s2, off);
                }
                float mu  = s  * (1.0f / HDIM);
                float var = s2 * (1.0f / HDIM) - mu * mu;
                float rs  = rsqrtf(var + 1e-5f);
                int m = w * 16 + quad * 4 + reg;
                #pragma unroll
                for (int nt = 0; nt < 8; ++nt) {
                    float x = (xv[nt] - mu) * rs * lgv[nt] + lbv[nt];
                    x = gelu_exact(x);
                    sH[m * 136 + nt * 16 + n0] = f2bf(x);
                }
            }
        }
        __syncthreads();

        // GEMM2: h[64x128] x W2T[g][n=64][k=128]
        const unsigned short* W2Tg = W2T + (size_t)g * 64 * 128;
        f32x4 acc2[4];
        #pragma unroll
        for (int nt2 = 0; nt2 < 4; ++nt2) acc2[nt2] = (f32x4){0.f, 0.f, 0.f, 0.f};

        #pragma unroll
        for (int ks2 = 0; ks2 < 4; ++ks2) {
            s16x8 a2 = *(const s16x8*)(&sH[(w * 16 + n0) * 136 + ks2 * 32 + quad * 8]);
            #pragma unroll
            for (int nt2 = 0; nt2 < 4; ++nt2) {
                s16x8 b2f = *(const s16x8*)(W2Tg + (size_t)(nt2 * 16 + n0) * 128 + ks2 * 32 + quad * 8);
                acc2[nt2] = __builtin_amdgcn_mfma_f32_16x16x32_bf16(a2, b2f, acc2[nt2], 0, 0, 0);
            }
        }

        // epilogue: GELU + dot W3 + quad reduce + write
        {
            float b2v[4], w3v[4];
            #pragma unroll
            for (int nt2 = 0; nt2 < 4; ++nt2) {
                int c = nt2 * 16 + n0;
                b2v[nt2] = b2[g * 64 + c];
                w3v[nt2] = W3[g * 64 + c];
            }
            float bias3 = b3[g];
            int lo = (g == 0) ? 0   : (g == 1) ? gs1 : gs2;
            int hi = (g == 0) ? gs1 : (g == 1) ? gs2 : E;
            #pragma unroll
            for (int reg = 0; reg < 4; ++reg) {
                float sacc = 0.f;
                #pragma unroll
                for (int nt2 = 0; nt2 < 4; ++nt2)
                    sacc += gelu_exact(acc2[nt2][reg] + b2v[nt2]) * w3v[nt2];
                #pragma unroll
                for (int off = 1; off < 16; off <<= 1)
                    sacc += __shfl_xor(sacc, off);
                if (n0 == 0) {
                    int p = pos0 + w * 16 + quad * 4 + reg;
                    if (p >= lo && p < hi) out[p] = sacc + bias3;
                }
            }
        }
        __syncthreads();   // protect sH before next group iteration
    }
}

extern "C" void kernel_launch(void* const* d_in, const int* in_sizes, int n_in,
                              void* d_out, int out_size, void* d_ws, size_t ws_size,
                              hipStream_t stream) {
    const float* emb    = (const float*)d_in[0];
    const int*   edges  = (const int*)  d_in[1];
    const int*   groups = (const int*)  d_in[2];
    const float* W1     = (const float*)d_in[3];
    const float* b1     = (const float*)d_in[4];
    const float* lng    = (const float*)d_in[5];
    const float* lnb    = (const float*)d_in[6];
    const float* W2     = (const float*)d_in[7];
    const float* b2     = (const float*)d_in[8];
    const float* W3     = (const float*)d_in[9];
    const float* b3     = (const float*)d_in[10];
    float* out = (float*)d_out;
    int E = in_sizes[2];

    int nChunks = (E + 1023) / 1024;
    int* counts = (int*)d_ws;
    int* bbase  = counts + (size_t)nChunks * 3;
    int* gstart = bbase  + (size_t)nChunks * 3;
    int* sorted = gstart + 4;
    unsigned short* W1T = (unsigned short*)(((uintptr_t)(sorted + E) + 15) & ~(uintptr_t)15);
    unsigned short* W2T = W1T + (size_t)3 * 128 * 256;   // +196608 B (16B aligned)

    k_hist   <<<dim3(nChunks), dim3(256), 0, stream>>>(groups, E, counts);
    k_scan   <<<dim3(1),       dim3(192), 0, stream>>>(counts, nChunks, bbase, gstart, E);
    k_scatter<<<dim3(nChunks), dim3(64),  0, stream>>>(groups, E, bbase, gstart, sorted);
    k_prep   <<<dim3(60),      dim3(256), 0, stream>>>(W1, W2, W1T, W2T);

    int nTiles = (E + TM - 1) / TM;
    k_mlp<<<dim3(nTiles), dim3(256), 0, stream>>>(
        emb, edges, sorted, gstart, W1T, b1, lng, lnb, W2T, b2, W3, b3, out, E);
}

// Round 3
// 376.875 us; speedup vs baseline: 1.9187x; 1.2559x over previous
//
#include <hip/hip_runtime.h>
#include <math.h>
#include <stdint.h>

#define HDIM 128
#define TM 128  // edges per block in the fused MLP kernel (32 per wave)

typedef short s16x8 __attribute__((ext_vector_type(8)));      // 8 bf16 (4 VGPRs) MFMA A/B frag
typedef float f32x4 __attribute__((ext_vector_type(4)));      // MFMA C/D frag
typedef unsigned short ushort8 __attribute__((ext_vector_type(8)));

// fp32 -> bf16 round-to-nearest-even
__device__ __forceinline__ unsigned short f2bf(float x) {
    unsigned u = __float_as_uint(x);
    u += 0x7FFFu + ((u >> 16) & 1u);
    return (unsigned short)(u >> 16);
}

// Abramowitz-Stegun 7.1.26: |err| <= 1.5e-7 absolute. ~14 VALU ops vs libm ~40.
__device__ __forceinline__ float erf_fast(float x) {
    float ax = fabsf(x);
    float t = __builtin_amdgcn_rcpf(fmaf(0.3275911f, ax, 1.0f));
    float p =        fmaf(t, 1.061405429f, -1.453152027f);
    p = fmaf(t, p, 1.421413741f);
    p = fmaf(t, p, -0.284496736f);
    p = fmaf(t, p, 0.254829592f);
    float e = exp2f(ax * ax * -1.4426950408889634f);
    float r = 1.0f - p * t * e;
    return copysignf(r, x);
}

__device__ __forceinline__ float gelu_exact(float x) {
    return 0.5f * x * (1.0f + erf_fast(x * 0.70710678118654752440f));
}

// ---------------- stable counting-sort kernels ----------------

__global__ void k_hist(const int* __restrict__ groups, int E, int* __restrict__ counts) {
    __shared__ int c[3];
    int t = threadIdx.x;
    if (t < 3) c[t] = 0;
    __syncthreads();
    int base = blockIdx.x * 1024;
    for (int i = t; i < 1024; i += 256) {
        int e = base + i;
        if (e < E) atomicAdd(&c[groups[e]], 1);
    }
    __syncthreads();
    if (t < 3) counts[blockIdx.x * 3 + t] = c[t];
}

__global__ void k_scan(const int* __restrict__ counts, int nChunks,
                       int* __restrict__ bbase, int* __restrict__ gstart, int E) {
    __shared__ int tot[3];
    int t = threadIdx.x;         // block = 192
    int lane = t & 63;
    int g = t >> 6;              // 0..2
    int carry = 0;
    for (int base = 0; base < nChunks; base += 64) {
        int b = base + lane;
        int v = (b < nChunks) ? counts[b * 3 + g] : 0;
        int sc = v;
        #pragma unroll
        for (int off = 1; off < 64; off <<= 1) {
            int u = __shfl_up(sc, off);
            if (lane >= off) sc += u;
        }
        if (b < nChunks) bbase[b * 3 + g] = carry + sc - v;
        carry += __shfl(sc, 63);
    }
    if (lane == 0) tot[g] = carry;
    __syncthreads();
    if (t == 0) {
        gstart[0] = 0;
        gstart[1] = tot[0];
        gstart[2] = tot[0] + tot[1];
        gstart[3] = E;
    }
}

__global__ void k_scatter(const int* __restrict__ groups, int E,
                          const int* __restrict__ bbase, const int* __restrict__ gstart,
                          int* __restrict__ sorted) {
    int b = blockIdx.x;
    int lane = threadIdx.x;  // block = 64 (one wave)
    int run0 = gstart[0] + bbase[b * 3 + 0];
    int run1 = gstart[1] + bbase[b * 3 + 1];
    int run2 = gstart[2] + bbase[b * 3 + 2];
    unsigned long long lt = (1ull << lane) - 1ull;
    for (int p = 0; p < 16; ++p) {
        int e = b * 1024 + p * 64 + lane;
        int g = (e < E) ? groups[e] : 3;
        unsigned long long m0 = __ballot(g == 0);
        unsigned long long m1 = __ballot(g == 1);
        unsigned long long m2 = __ballot(g == 2);
        int pos = 0;
        if (g == 0) pos = run0 + __popcll(m0 & lt);
        else if (g == 1) pos = run1 + __popcll(m1 & lt);
        else if (g == 2) pos = run2 + __popcll(m2 & lt);
        if (e < E) sorted[pos] = e;
        run0 += __popcll(m0);
        run1 += __popcll(m1);
        run2 += __popcll(m2);
    }
}

// ---------------- prep: emb fp32->bf16, plus W1/W2 transpose+convert ----------------
__global__ void k_prep(const float* __restrict__ emb, int embElems, int embBlocks,
                       const float* __restrict__ W1, const float* __restrict__ W2,
                       unsigned short* __restrict__ embB,
                       unsigned short* __restrict__ W1T, unsigned short* __restrict__ W2T) {
    if ((int)blockIdx.x < embBlocks) {
        int i = (blockIdx.x * 256 + threadIdx.x) * 8;
        if (i + 8 <= embElems) {
            float4 a = *(const float4*)(emb + i);
            float4 b = *(const float4*)(emb + i + 4);
            ushort8 o;
            o[0] = f2bf(a.x); o[1] = f2bf(a.y); o[2] = f2bf(a.z); o[3] = f2bf(a.w);
            o[4] = f2bf(b.x); o[5] = f2bf(b.y); o[6] = f2bf(b.z); o[7] = f2bf(b.w);
            *(ushort8*)(embB + i) = o;
        } else {
            for (int j = i; j < embElems; ++j) embB[j] = f2bf(emb[j]);
        }
        return;
    }
    int idx = (blockIdx.x - embBlocks) * 256 + threadIdx.x;
    if (idx < 3 * 32 * 128) {                    // W1T[g][n=128][k=256]
        int g  = idx >> 12;
        int r  = idx & 4095;
        int kc = r >> 7;                         // k0 = kc*8
        int n  = r & 127;
        const float* src = W1 + (size_t)g * 256 * 128 + (size_t)(kc * 8) * 128 + n;
        ushort8 o;
        #pragma unroll
        for (int j = 0; j < 8; ++j) o[j] = f2bf(src[j * 128]);
        *(ushort8*)(W1T + ((size_t)(g * 128 + n)) * 256 + kc * 8) = o;
    } else if (idx < 3 * 32 * 128 + 3 * 16 * 64) {
        int r2 = idx - 3 * 32 * 128;             // W2T[g][n=64][k=128]
        int g  = r2 >> 10;
        int r  = r2 & 1023;
        int kc = r >> 6;
        int n  = r & 63;
        const float* src = W2 + (size_t)g * 128 * 64 + (size_t)(kc * 8) * 64 + n;
        ushort8 o;
        #pragma unroll
        for (int j = 0; j < 8; ++j) o[j] = f2bf(src[j * 64]);
        *(ushort8*)(W2T + ((size_t)(g * 64 + n)) * 128 + kc * 8) = o;
    }
}

// ---------------- fused per-edge MLP (MFMA bf16) ----------------
// Block: 256 thr = 4 waves; TM=128 edges, M=32 rows per wave (2 m-tiles of 16).
// Each B-frag (global, L1/L2) feeds 2 MFMAs. A-frags load directly from bf16 embB.
__global__ __launch_bounds__(256, 3)
void k_mlp(const unsigned short* __restrict__ embB,
           const int* __restrict__ edges,
           const int* __restrict__ sorted,
           const int* __restrict__ gstart,
           const unsigned short* __restrict__ W1T,
           const float* __restrict__ b1,
           const float* __restrict__ lng, const float* __restrict__ lnb,
           const unsigned short* __restrict__ W2T,
           const float* __restrict__ b2,
           const float* __restrict__ W3, const float* __restrict__ b3,
           float* __restrict__ out, int E)
{
    __shared__ unsigned short sH[128 * 136];   // 34816 B; stride 136 keeps A2 reads ~conflict-free

    const int t    = threadIdx.x;
    const int w    = t >> 6;        // wave 0..3
    const int lane = t & 63;
    const int n0   = lane & 15;     // MFMA 16-index
    const int quad = lane >> 4;     // MFMA k-quad / D row-group

    const int pos0 = blockIdx.x * TM;

    const unsigned short* urow[2];
    const unsigned short* vrow[2];
    #pragma unroll
    for (int mt = 0; mt < 2; ++mt) {
        int p = pos0 + w * 32 + mt * 16 + n0;
        int pc = p < E ? p : E - 1;
        int e  = sorted[pc];
        urow[mt] = embB + (size_t)edges[2 * e]     * HDIM;
        vrow[mt] = embB + (size_t)edges[2 * e + 1] * HDIM;
    }

    int gs1 = gstart[1], gs2 = gstart[2];
    int plast = (pos0 + TM - 1 < E) ? pos0 + TM - 1 : E - 1;
    int g0 = (pos0  >= gs2) ? 2 : (pos0  >= gs1) ? 1 : 0;
    int g1 = (plast >= gs2) ? 2 : (plast >= gs1) ? 1 : 0;

    for (int g = g0; g <= g1; ++g) {
        const unsigned short* W1Tg = W1T + (size_t)g * 128 * 256;

        f32x4 acc[2][8];
        #pragma unroll
        for (int mt = 0; mt < 2; ++mt)
            #pragma unroll
            for (int nt = 0; nt < 8; ++nt) acc[mt][nt] = (f32x4){0.f, 0.f, 0.f, 0.f};

        #pragma unroll
        for (int ks = 0; ks < 8; ++ks) {
            s16x8 af[2];
            #pragma unroll
            for (int mt = 0; mt < 2; ++mt)
                af[mt] = *(const s16x8*)((ks < 4 ? urow[mt] : vrow[mt]) + ((ks * 32) & (HDIM - 1)) + quad * 8);
            #pragma unroll
            for (int nt = 0; nt < 8; ++nt) {
                s16x8 bfrag = *(const s16x8*)(W1Tg + (size_t)(nt * 16 + n0) * 256 + ks * 32 + quad * 8);
                #pragma unroll
                for (int mt = 0; mt < 2; ++mt)
                    acc[mt][nt] = __builtin_amdgcn_mfma_f32_16x16x32_bf16(af[mt], bfrag, acc[mt][nt], 0, 0, 0);
            }
        }

        // bias + LayerNorm + GELU; D layout: row = quad*4+reg, col = nt*16+n0
        {
            float b1v[8], lgv[8], lbv[8];
            #pragma unroll
            for (int nt = 0; nt < 8; ++nt) {
                int c = nt * 16 + n0;
                b1v[nt] = b1[g * HDIM + c];
                lgv[nt] = lng[g * HDIM + c];
                lbv[nt] = lnb[g * HDIM + c];
            }
            #pragma unroll
            for (int mt = 0; mt < 2; ++mt) {
                #pragma unroll
                for (int reg = 0; reg < 4; ++reg) {
                    float s = 0.f, s2 = 0.f;
                    float xv[8];
                    #pragma unroll
                    for (int nt = 0; nt < 8; ++nt) {
                        float x = acc[mt][nt][reg] + b1v[nt];
                        xv[nt] = x; s += x; s2 += x * x;
                    }
                    #pragma unroll
                    for (int off = 1; off < 16; off <<= 1) {
                        s  += __shfl_xor(s,  off);
                        s2 += __shfl_xor(s2, off);
                    }
                    float mu  = s  * (1.0f / HDIM);
                    float var = s2 * (1.0f / HDIM) - mu * mu;
                    float rs  = rsqrtf(var + 1e-5f);
                    int m = w * 32 + mt * 16 + quad * 4 + reg;
                    #pragma unroll
                    for (int nt = 0; nt < 8; ++nt) {
                        float x = (xv[nt] - mu) * rs * lgv[nt] + lbv[nt];
                        x = gelu_exact(x);
                        sH[m * 136 + nt * 16 + n0] = f2bf(x);
                    }
                }
            }
        }
        __syncthreads();

        // GEMM2: h[128x128] x W2T[g][n=64][k=128]
        const unsigned short* W2Tg = W2T + (size_t)g * 64 * 128;
        f32x4 acc2[2][4];
        #pragma unroll
        for (int mt = 0; mt < 2; ++mt)
            #pragma unroll
            for (int nt2 = 0; nt2 < 4; ++nt2) acc2[mt][nt2] = (f32x4){0.f, 0.f, 0.f, 0.f};

        #pragma unroll
        for (int ks2 = 0; ks2 < 4; ++ks2) {
            s16x8 a2[2];
            #pragma unroll
            for (int mt = 0; mt < 2; ++mt)
                a2[mt] = *(const s16x8*)(&sH[(w * 32 + mt * 16 + n0) * 136 + ks2 * 32 + quad * 8]);
            #pragma unroll
            for (int nt2 = 0; nt2 < 4; ++nt2) {
                s16x8 b2f = *(const s16x8*)(W2Tg + (size_t)(nt2 * 16 + n0) * 128 + ks2 * 32 + quad * 8);
                #pragma unroll
                for (int mt = 0; mt < 2; ++mt)
                    acc2[mt][nt2] = __builtin_amdgcn_mfma_f32_16x16x32_bf16(a2[mt], b2f, acc2[mt][nt2], 0, 0, 0);
            }
        }

        // epilogue: GELU + dot W3 + quad reduce + write
        {
            float b2v[4], w3v[4];
            #pragma unroll
            for (int nt2 = 0; nt2 < 4; ++nt2) {
                int c = nt2 * 16 + n0;
                b2v[nt2] = b2[g * 64 + c];
                w3v[nt2] = W3[g * 64 + c];
            }
            float bias3 = b3[g];
            int lo = (g == 0) ? 0   : (g == 1) ? gs1 : gs2;
            int hi = (g == 0) ? gs1 : (g == 1) ? gs2 : E;
            #pragma unroll
            for (int mt = 0; mt < 2; ++mt) {
                #pragma unroll
                for (int reg = 0; reg < 4; ++reg) {
                    float sacc = 0.f;
                    #pragma unroll
                    for (int nt2 = 0; nt2 < 4; ++nt2)
                        sacc += gelu_exact(acc2[mt][nt2][reg] + b2v[nt2]) * w3v[nt2];
                    #pragma unroll
                    for (int off = 1; off < 16; off <<= 1)
                        sacc += __shfl_xor(sacc, off);
                    if (n0 == 0) {
                        int p = pos0 + w * 32 + mt * 16 + quad * 4 + reg;
                        if (p >= lo && p < hi) out[p] = sacc + bias3;
                    }
                }
            }
        }
        __syncthreads();   // protect sH before next group iteration
    }
}

extern "C" void kernel_launch(void* const* d_in, const int* in_sizes, int n_in,
                              void* d_out, int out_size, void* d_ws, size_t ws_size,
                              hipStream_t stream) {
    const float* emb    = (const float*)d_in[0];
    const int*   edges  = (const int*)  d_in[1];
    const int*   groups = (const int*)  d_in[2];
    const float* W1     = (const float*)d_in[3];
    const float* b1     = (const float*)d_in[4];
    const float* lng    = (const float*)d_in[5];
    const float* lnb    = (const float*)d_in[6];
    const float* W2     = (const float*)d_in[7];
    const float* b2     = (const float*)d_in[8];
    const float* W3     = (const float*)d_in[9];
    const float* b3     = (const float*)d_in[10];
    float* out = (float*)d_out;
    int E        = in_sizes[2];
    int embElems = in_sizes[0];

    int nChunks = (E + 1023) / 1024;
    int embBlocks = (embElems / 8 + 255) / 256;

    // workspace layout
    unsigned short* embB = (unsigned short*)d_ws;
    unsigned short* W1T  = embB + (((size_t)embElems + 7) & ~(size_t)7);
    unsigned short* W2T  = W1T + (size_t)3 * 128 * 256;
    int* counts = (int*)(W2T + (size_t)3 * 64 * 128);
    int* bbase  = counts + (size_t)nChunks * 3;
    int* gstart = bbase  + (size_t)nChunks * 3;
    int* sorted = gstart + 4;

    k_hist   <<<dim3(nChunks),        dim3(256), 0, stream>>>(groups, E, counts);
    k_scan   <<<dim3(1),              dim3(192), 0, stream>>>(counts, nChunks, bbase, gstart, E);
    k_scatter<<<dim3(nChunks),        dim3(64),  0, stream>>>(groups, E, bbase, gstart, sorted);
    k_prep   <<<dim3(embBlocks + 60), dim3(256), 0, stream>>>(emb, embElems, embBlocks, W1, W2, embB, W1T, W2T);

    int nTiles = (E + TM - 1) / TM;
    k_mlp<<<dim3(nTiles), dim3(256), 0, stream>>>(
        embB, edges, sorted, gstart, W1T, b1, lng, lnb, W2T, b2, W3, b3, out, E);
}

// Round 4
// 265.095 us; speedup vs baseline: 2.7277x; 1.4217x over previous
//
#include <hip/hip_runtime.h>
#include <math.h>
#include <stdint.h>

#define HDIM 128
#define TM 128  // edges per block in the fused MLP kernel (32 per wave)

typedef short s16x8 __attribute__((ext_vector_type(8)));      // 8 bf16 (4 VGPRs) MFMA A/B frag
typedef float f32x4 __attribute__((ext_vector_type(4)));      // MFMA C/D frag
typedef unsigned short ushort8 __attribute__((ext_vector_type(8)));

// fp32 -> bf16 round-to-nearest-even
__device__ __forceinline__ unsigned short f2bf(float x) {
    unsigned u = __float_as_uint(x);
    u += 0x7FFFu + ((u >> 16) & 1u);
    return (unsigned short)(u >> 16);
}

// Abramowitz-Stegun 7.1.26: |err| <= 1.5e-7 absolute.
__device__ __forceinline__ float erf_fast(float x) {
    float ax = fabsf(x);
    float t = __builtin_amdgcn_rcpf(fmaf(0.3275911f, ax, 1.0f));
    float p =        fmaf(t, 1.061405429f, -1.453152027f);
    p = fmaf(t, p, 1.421413741f);
    p = fmaf(t, p, -0.284496736f);
    p = fmaf(t, p, 0.254829592f);
    float e = exp2f(ax * ax * -1.4426950408889634f);
    float r = 1.0f - p * t * e;
    return copysignf(r, x);
}

__device__ __forceinline__ float gelu_exact(float x) {
    return 0.5f * x * (1.0f + erf_fast(x * 0.70710678118654752440f));
}

// async global->LDS 16B per lane; LDS layout must be linear (wave-uniform base + lane*16)
__device__ __forceinline__ void async_cp16(void* lds_dst, const void* g_src) {
    __builtin_amdgcn_global_load_lds(
        (const __attribute__((address_space(1))) unsigned int*)g_src,
        (__attribute__((address_space(3))) unsigned int*)lds_dst,
        16, 0, 0);
}

// ---------------- stable counting-sort kernels ----------------

__global__ void k_hist(const int* __restrict__ groups, int E, int* __restrict__ counts) {
    __shared__ int c[3];
    int t = threadIdx.x;
    if (t < 3) c[t] = 0;
    __syncthreads();
    int base = blockIdx.x * 1024;
    for (int i = t; i < 1024; i += 256) {
        int e = base + i;
        if (e < E) atomicAdd(&c[groups[e]], 1);
    }
    __syncthreads();
    if (t < 3) counts[blockIdx.x * 3 + t] = c[t];
}

__global__ void k_scan(const int* __restrict__ counts, int nChunks,
                       int* __restrict__ bbase, int* __restrict__ gstart, int E) {
    __shared__ int tot[3];
    int t = threadIdx.x;         // block = 192
    int lane = t & 63;
    int g = t >> 6;              // 0..2
    int carry = 0;
    for (int base = 0; base < nChunks; base += 64) {
        int b = base + lane;
        int v = (b < nChunks) ? counts[b * 3 + g] : 0;
        int sc = v;
        #pragma unroll
        for (int off = 1; off < 64; off <<= 1) {
            int u = __shfl_up(sc, off);
            if (lane >= off) sc += u;
        }
        if (b < nChunks) bbase[b * 3 + g] = carry + sc - v;
        carry += __shfl(sc, 63);
    }
    if (lane == 0) tot[g] = carry;
    __syncthreads();
    if (t == 0) {
        gstart[0] = 0;
        gstart[1] = tot[0];
        gstart[2] = tot[0] + tot[1];
        gstart[3] = E;
    }
}

__global__ void k_scatter(const int* __restrict__ groups, int E,
                          const int* __restrict__ bbase, const int* __restrict__ gstart,
                          int* __restrict__ sorted) {
    int b = blockIdx.x;
    int lane = threadIdx.x;  // block = 64 (one wave)
    int run0 = gstart[0] + bbase[b * 3 + 0];
    int run1 = gstart[1] + bbase[b * 3 + 1];
    int run2 = gstart[2] + bbase[b * 3 + 2];
    unsigned long long lt = (1ull << lane) - 1ull;
    for (int p = 0; p < 16; ++p) {
        int e = b * 1024 + p * 64 + lane;
        int g = (e < E) ? groups[e] : 3;
        unsigned long long m0 = __ballot(g == 0);
        unsigned long long m1 = __ballot(g == 1);
        unsigned long long m2 = __ballot(g == 2);
        int pos = 0;
        if (g == 0) pos = run0 + __popcll(m0 & lt);
        else if (g == 1) pos = run1 + __popcll(m1 & lt);
        else if (g == 2) pos = run2 + __popcll(m2 & lt);
        if (e < E) sorted[pos] = e;
        run0 += __popcll(m0);
        run1 += __popcll(m1);
        run2 += __popcll(m2);
    }
}

// ---------------- prep: emb fp32->bf16; W1 swizzled+transposed; W2 transposed ----------------
// W1S[g][n][gk' * 8 .. +7] where gk' = gk ^ (n & 7), gk = k/8  (bank-swizzle for LDS reads)
// W2T[g][n=64][k=128]
__global__ void k_prep(const float* __restrict__ emb, int embElems, int embBlocks,
                       const float* __restrict__ W1, const float* __restrict__ W2,
                       unsigned short* __restrict__ embB,
                       unsigned short* __restrict__ W1S, unsigned short* __restrict__ W2T) {
    if ((int)blockIdx.x < embBlocks) {
        int i = (blockIdx.x * 256 + threadIdx.x) * 8;
        if (i + 8 <= embElems) {
            float4 a = *(const float4*)(emb + i);
            float4 b = *(const float4*)(emb + i + 4);
            ushort8 o;
            o[0] = f2bf(a.x); o[1] = f2bf(a.y); o[2] = f2bf(a.z); o[3] = f2bf(a.w);
            o[4] = f2bf(b.x); o[5] = f2bf(b.y); o[6] = f2bf(b.z); o[7] = f2bf(b.w);
            *(ushort8*)(embB + i) = o;
        } else {
            for (int j = i; j < embElems; ++j) embB[j] = f2bf(emb[j]);
        }
        return;
    }
    int idx = (blockIdx.x - embBlocks) * 256 + threadIdx.x;
    if (idx < 3 * 32 * 128) {                    // W1S: task = (g, gk, n)
        int g  = idx >> 12;
        int r  = idx & 4095;
        int gk = r >> 7;                         // k-granule 0..31 (k0 = gk*8)
        int n  = r & 127;
        const float* src = W1 + (size_t)g * 256 * 128 + (size_t)(gk * 8) * 128 + n;
        ushort8 o;
        #pragma unroll
        for (int j = 0; j < 8; ++j) o[j] = f2bf(src[j * 128]);
        int gks = gk ^ (n & 7);                  // bank swizzle
        *(ushort8*)(W1S + ((size_t)(g * 128 + n)) * 256 + gks * 8) = o;
    } else if (idx < 3 * 32 * 128 + 3 * 16 * 64) {
        int r2 = idx - 3 * 32 * 128;             // W2T[g][n=64][k=128]
        int g  = r2 >> 10;
        int r  = r2 & 1023;
        int kc = r >> 6;
        int n  = r & 63;
        const float* src = W2 + (size_t)g * 128 * 64 + (size_t)(kc * 8) * 64 + n;
        ushort8 o;
        #pragma unroll
        for (int j = 0; j < 8; ++j) o[j] = f2bf(src[j * 64]);
        *(ushort8*)(W2T + ((size_t)(g * 64 + n)) * 128 + kc * 8) = o;
    }
}

// ---------------- fused per-edge MLP (MFMA bf16, LDS-staged W1) ----------------
// Block: 256 thr = 4 waves; TM=128 edges, M=32 per wave (2 m-tiles).
// A-frags: preloaded into registers (16 b128) before the group loop.
// GEMM1 B: W1S[g] staged to LDS (64KB) via global_load_lds, read as ds_read_b128.
// sH overlays the dead W1 LDS region. GEMM2 B: global W2T (16KB, L1-resident).
__global__ __launch_bounds__(256, 2)
void k_mlp(const unsigned short* __restrict__ embB,
           const int* __restrict__ edges,
           const int* __restrict__ sorted,
           const int* __restrict__ gstart,
           const unsigned short* __restrict__ W1S,
           const float* __restrict__ b1,
           const float* __restrict__ lng, const float* __restrict__ lnb,
           const unsigned short* __restrict__ W2T,
           const float* __restrict__ b2,
           const float* __restrict__ W3, const float* __restrict__ b3,
           float* __restrict__ out, int E)
{
    __shared__ unsigned char smem[65536];      // W1s [128][256] bf16 (64KB); sH overlays
    unsigned short* W1s = (unsigned short*)smem;
    unsigned short* sH  = (unsigned short*)smem;   // [128][136] bf16 (34816 B), after GEMM1

    const int t    = threadIdx.x;
    const int w    = t >> 6;        // wave 0..3
    const int lane = t & 63;
    const int n0   = lane & 15;     // MFMA 16-index
    const int quad = lane >> 4;     // MFMA k-quad / D row-group

    const int pos0 = blockIdx.x * TM;

    int gs1 = gstart[1], gs2 = gstart[2];
    int plast = (pos0 + TM - 1 < E) ? pos0 + TM - 1 : E - 1;
    int g0 = (pos0  >= gs2) ? 2 : (pos0  >= gs1) ? 1 : 0;
    int g1 = (plast >= gs2) ? 2 : (plast >= gs1) ? 1 : 0;

    // ---- prefetch all A-fragments into registers (held across the g-loop) ----
    const unsigned short* urow[2];
    const unsigned short* vrow[2];
    #pragma unroll
    for (int mt = 0; mt < 2; ++mt) {
        int p = pos0 + w * 32 + mt * 16 + n0;
        int pc = p < E ? p : E - 1;
        int e  = sorted[pc];
        urow[mt] = embB + (size_t)edges[2 * e]     * HDIM;
        vrow[mt] = embB + (size_t)edges[2 * e + 1] * HDIM;
    }
    s16x8 afr[8][2];
    #pragma unroll
    for (int ks = 0; ks < 8; ++ks)
        #pragma unroll
        for (int mt = 0; mt < 2; ++mt)
            afr[ks][mt] = *(const s16x8*)((ks < 4 ? urow[mt] : vrow[mt]) + ((ks * 32) & (HDIM - 1)) + quad * 8);

    for (int g = g0; g <= g1; ++g) {
        // ---- stage W1S[g] (64KB) into LDS; linear layout (swizzle already in global) ----
        {
            const unsigned char* src = (const unsigned char*)(W1S + (size_t)g * 128 * 256);
            #pragma unroll
            for (int r = 0; r < 16; ++r) {
                int off = r * 4096 + t * 16;
                async_cp16(smem + off, src + off);
            }
        }

        // hoist epilogue constants (overlap staging/GEMM1)
        float b1v[8], lgv[8], lbv[8];
        #pragma unroll
        for (int nt = 0; nt < 8; ++nt) {
            int c = nt * 16 + n0;
            b1v[nt] = b1[g * HDIM + c];
            lgv[nt] = lng[g * HDIM + c];
            lbv[nt] = lnb[g * HDIM + c];
        }
        float b2v[4], w3v[4];
        #pragma unroll
        for (int nt2 = 0; nt2 < 4; ++nt2) {
            int c = nt2 * 16 + n0;
            b2v[nt2] = b2[g * 64 + c];
            w3v[nt2] = W3[g * 64 + c];
        }
        float bias3 = b3[g];

        __syncthreads();   // drains vmcnt: staging + (first iter) A-frags

        // ---- GEMM1: [128 x 256] x [256 x 128], B from LDS ----
        f32x4 acc[2][8];
        #pragma unroll
        for (int mt = 0; mt < 2; ++mt)
            #pragma unroll
            for (int nt = 0; nt < 8; ++nt) acc[mt][nt] = (f32x4){0.f, 0.f, 0.f, 0.f};

        #pragma unroll
        for (int ks = 0; ks < 8; ++ks) {
            #pragma unroll
            for (int nt = 0; nt < 8; ++nt) {
                int gk = (ks * 4 + quad) ^ (n0 & 7);          // de-swizzle
                s16x8 bfrag = *(const s16x8*)(&W1s[(nt * 16 + n0) * 256 + gk * 8]);
                acc[0][nt] = __builtin_amdgcn_mfma_f32_16x16x32_bf16(afr[ks][0], bfrag, acc[0][nt], 0, 0, 0);
                acc[1][nt] = __builtin_amdgcn_mfma_f32_16x16x32_bf16(afr[ks][1], bfrag, acc[1][nt], 0, 0, 0);
            }
        }
        __syncthreads();   // W1s dead; sH region becomes writable

        // ---- bias + LayerNorm + GELU; D layout: row = quad*4+reg, col = nt*16+n0 ----
        #pragma unroll
        for (int mt = 0; mt < 2; ++mt) {
            #pragma unroll
            for (int reg = 0; reg < 4; ++reg) {
                float s = 0.f, s2 = 0.f;
                float xv[8];
                #pragma unroll
                for (int nt = 0; nt < 8; ++nt) {
                    float x = acc[mt][nt][reg] + b1v[nt];
                    xv[nt] = x; s += x; s2 += x * x;
                }
                #pragma unroll
                for (int off = 1; off < 16; off <<= 1) {
                    s  += __shfl_xor(s,  off);
                    s2 += __shfl_xor(s2, off);
                }
                float mu  = s  * (1.0f / HDIM);
                float var = s2 * (1.0f / HDIM) - mu * mu;
                float rs  = rsqrtf(var + 1e-5f);
                int m = w * 32 + mt * 16 + quad * 4 + reg;
                #pragma unroll
                for (int nt = 0; nt < 8; ++nt) {
                    float x = (xv[nt] - mu) * rs * lgv[nt] + lbv[nt];
                    x = gelu_exact(x);
                    sH[m * 136 + nt * 16 + n0] = f2bf(x);
                }
            }
        }
        __syncthreads();

        // ---- GEMM2: h[128x128] x W2T[g][n=64][k=128], A from sH, B from global ----
        const unsigned short* W2Tg = W2T + (size_t)g * 64 * 128;
        f32x4 acc2[2][4];
        #pragma unroll
        for (int mt = 0; mt < 2; ++mt)
            #pragma unroll
            for (int nt2 = 0; nt2 < 4; ++nt2) acc2[mt][nt2] = (f32x4){0.f, 0.f, 0.f, 0.f};

        #pragma unroll
        for (int ks2 = 0; ks2 < 4; ++ks2) {
            s16x8 a2[2];
            #pragma unroll
            for (int mt = 0; mt < 2; ++mt)
                a2[mt] = *(const s16x8*)(&sH[(w * 32 + mt * 16 + n0) * 136 + ks2 * 32 + quad * 8]);
            #pragma unroll
            for (int nt2 = 0; nt2 < 4; ++nt2) {
                s16x8 b2f = *(const s16x8*)(W2Tg + (size_t)(nt2 * 16 + n0) * 128 + ks2 * 32 + quad * 8);
                #pragma unroll
                for (int mt = 0; mt < 2; ++mt)
                    acc2[mt][nt2] = __builtin_amdgcn_mfma_f32_16x16x32_bf16(a2[mt], b2f, acc2[mt][nt2], 0, 0, 0);
            }
        }

        // ---- epilogue: GELU + dot W3 + quad reduce + write ----
        {
            int lo = (g == 0) ? 0   : (g == 1) ? gs1 : gs2;
            int hi = (g == 0) ? gs1 : (g == 1) ? gs2 : E;
            #pragma unroll
            for (int mt = 0; mt < 2; ++mt) {
                #pragma unroll
                for (int reg = 0; reg < 4; ++reg) {
                    float sacc = 0.f;
                    #pragma unroll
                    for (int nt2 = 0; nt2 < 4; ++nt2)
                        sacc += gelu_exact(acc2[mt][nt2][reg] + b2v[nt2]) * w3v[nt2];
                    #pragma unroll
                    for (int off = 1; off < 16; off <<= 1)
                        sacc += __shfl_xor(sacc, off);
                    if (n0 == 0) {
                        int p = pos0 + w * 32 + mt * 16 + quad * 4 + reg;
                        if (p >= lo && p < hi) out[p] = sacc + bias3;
                    }
                }
            }
        }
        __syncthreads();   // sH dead before next group's staging
    }
}

extern "C" void kernel_launch(void* const* d_in, const int* in_sizes, int n_in,
                              void* d_out, int out_size, void* d_ws, size_t ws_size,
                              hipStream_t stream) {
    const float* emb    = (const float*)d_in[0];
    const int*   edges  = (const int*)  d_in[1];
    const int*   groups = (const int*)  d_in[2];
    const float* W1     = (const float*)d_in[3];
    const float* b1     = (const float*)d_in[4];
    const float* lng    = (const float*)d_in[5];
    const float* lnb    = (const float*)d_in[6];
    const float* W2     = (const float*)d_in[7];
    const float* b2     = (const float*)d_in[8];
    const float* W3     = (const float*)d_in[9];
    const float* b3     = (const float*)d_in[10];
    float* out = (float*)d_out;
    int E        = in_sizes[2];
    int embElems = in_sizes[0];

    int nChunks = (E + 1023) / 1024;
    int embBlocks = (embElems / 8 + 255) / 256;

    // workspace layout
    unsigned short* embB = (unsigned short*)d_ws;
    unsigned short* W1S  = embB + (((size_t)embElems + 7) & ~(size_t)7);
    unsigned short* W2T  = W1S + (size_t)3 * 128 * 256;
    int* counts = (int*)(W2T + (size_t)3 * 64 * 128);
    int* bbase  = counts + (size_t)nChunks * 3;
    int* gstart = bbase  + (size_t)nChunks * 3;
    int* sorted = gstart + 4;

    k_hist   <<<dim3(nChunks),        dim3(256), 0, stream>>>(groups, E, counts);
    k_scan   <<<dim3(1),              dim3(192), 0, stream>>>(counts, nChunks, bbase, gstart, E);
    k_scatter<<<dim3(nChunks),        dim3(64),  0, stream>>>(groups, E, bbase, gstart, sorted);
    k_prep   <<<dim3(embBlocks + 60), dim3(256), 0, stream>>>(emb, embElems, embBlocks, W1, W2, embB, W1S, W2T);

    int nTiles = (E + TM - 1) / TM;
    k_mlp<<<dim3(nTiles), dim3(256), 0, stream>>>(
        embB, edges, sorted, gstart, W1S, b1, lng, lnb, W2T, b2, W3, b3, out, E);
}